// Round 18
// baseline (203.076 us; speedup 1.0000x reference)
//
#include <hip/hip_runtime.h>
#include <hip/hip_cooperative_groups.h>
#include <hip/hip_bf16.h>
#include <hip/hip_fp16.h>

namespace cg = cooperative_groups;

#define SVOX 13824   // 24*24*24
#define CIN 128
#define NHEAD 4
#define HDIM 32

// attention brick geometry: 2x4x8 voxels, 256 threads (4 lanes/voxel)
#define BD 2
#define BH 4
#define BW 8
#define WD (BD+2)
#define WH (BH+2)
#define WW (BW+2)
#define NWIN (WD*WH*WW)   // 240

typedef __attribute__((ext_vector_type(8))) short short8;
typedef __attribute__((ext_vector_type(8))) _Float16 half8;
typedef __attribute__((ext_vector_type(4))) float f32x4;
typedef __attribute__((ext_vector_type(2))) _Float16 h2v;
#if defined(__has_builtin)
#if __has_builtin(__builtin_amdgcn_fdot2)
#define HAVE_FDOT2 1
#endif
#if __has_builtin(__builtin_amdgcn_mov_dpp)
#define HAVE_DPP 1
#endif
#if __has_builtin(__builtin_amdgcn_cvt_pkrtz)
#define HAVE_PKRTZ 1
#endif
#endif

__device__ __forceinline__ unsigned short f2bf(float x) {
    unsigned u = __float_as_uint(x);
    u += 0x7FFFu + ((u >> 16) & 1u);
    return (unsigned short)(u >> 16);
}
__device__ __forceinline__ unsigned short f2h(float x) {
    return __builtin_bit_cast(unsigned short, (_Float16)x);
}
__device__ __forceinline__ __half2 u2h2(unsigned u) {
    union { unsigned u; __half2 h; } c; c.u = u; return c.h;
}
__device__ __forceinline__ float dot2h(unsigned a, unsigned b, float c) {
#ifdef HAVE_FDOT2
    return __builtin_amdgcn_fdot2(__builtin_bit_cast(h2v, a),
                                  __builtin_bit_cast(h2v, b), c, false);
#else
    __half2 p = __hmul2(u2h2(a), u2h2(b));
    return c + __low2float(p) + __high2float(p);
#endif
}
__device__ __forceinline__ float dot8h(uint4 a, uint4 b, float c) {
    c = dot2h(a.x, b.x, c); c = dot2h(a.y, b.y, c);
    c = dot2h(a.z, b.z, c); c = dot2h(a.w, b.w, c);
    return c;
}
template<int CTRL>
__device__ __forceinline__ float quad_dpp(float x) {
#ifdef HAVE_DPP
    return __int_as_float(__builtin_amdgcn_mov_dpp(__float_as_int(x), CTRL, 0xf, 0xf, true));
#else
    return __shfl_xor(x, (CTRL == 0xB1) ? 1 : 2);
#endif
}
__device__ __forceinline__ __half2 splat_h2(float x) {
#ifdef HAVE_PKRTZ
    auto v = __builtin_amdgcn_cvt_pkrtz(x, x);
    union { decltype(v) a; __half2 h; } c; c.a = v; return c.h;
#else
    return __float2half2_rn(x);
#endif
}

// ---------------------------------------------------------------------------
// Fused pipeline: phase1 qkv GEMM -> grid.sync -> phase2 attn -> grid.sync
// -> phase3 proj GEMM. Cooperative launch; grid-stride in each phase.
// ---------------------------------------------------------------------------
__global__ __launch_bounds__(256, 4) void fused_kernel(
    const float* __restrict__ X,
    const float* __restrict__ Wqkv,
    const float* __restrict__ bqkv,
    const float* __restrict__ Wp,
    const float* __restrict__ bp,
    const float* __restrict__ pos,
    float* __restrict__ out,
    ushort* __restrict__ q_out,
    ushort* __restrict__ k_out,
    ushort* __restrict__ v_out,
    ushort* __restrict__ attn_o,
    unsigned* __restrict__ pe)
{
    __shared__ __align__(16) unsigned char smem[34816];
    const int t = threadIdx.x;
    cg::grid_group grid = cg::this_grid();

    // ================= Phase 1: QKV GEMM (2592 tiles) =================
    {
        ushort* Wb = (ushort*)smem;                 // [64][136] bf16
        ushort* Xs = (ushort*)(smem + 17408);       // [64 s][72 k] bf16
        float*  T  = (float*)smem;                  // epilogue alias

        const int lane = t & 63, wid = t >> 6, l15 = lane & 15, g4 = lane >> 4;
        const int wm = (wid >> 1) * 32, wn = (wid & 1) * 32;
        const int sx = t & 63, kg = t >> 6;

        if (blockIdx.x == 0)
            for (int i = t; i < 27 * 16; i += 256) {
                int w = i >> 4, cp = i & 15;
                pe[i] = (unsigned)f2h(pos[(2 * cp) * 27 + w])
                      | ((unsigned)f2h(pos[(2 * cp + 1) * 27 + w]) << 16);
            }

        for (int idx = blockIdx.x; idx < 2592; idx += gridDim.x) {
            const int b  = idx / 1296;
            const int r  = idx - b * 1296;
            const int o0 = (r / 216) * 64;
            const int s0 = (r % 216) * 64;
            __syncthreads();   // prev-iter T reads vs new Wb writes

            #pragma unroll
            for (int i = 0; i < 8; i++) {
                int f = t + i * 256;
                int row = f >> 5, c4 = f & 31;
                float4 w = *(const float4*)(Wqkv + (size_t)(o0 + row) * CIN + c4 * 4);
                ushort4 u;
                u.x = f2bf(w.x); u.y = f2bf(w.y); u.z = f2bf(w.z); u.w = f2bf(w.w);
                *(ushort4*)(Wb + row * 136 + c4 * 4) = u;
            }

            f32x4 acc[2][2];
            #pragma unroll
            for (int mf = 0; mf < 2; mf++)
                #pragma unroll
                for (int nf = 0; nf < 2; nf++)
                    acc[mf][nf] = (f32x4){0.f, 0.f, 0.f, 0.f};

            for (int chunk = 0; chunk < 2; chunk++) {
                __syncthreads();
                ushort xk[16];
                #pragma unroll
                for (int i = 0; i < 16; i++) {
                    int k = kg * 16 + i;
                    xk[i] = f2bf(X[((size_t)b * CIN + chunk * 64 + k) * SVOX + s0 + sx]);
                }
                #pragma unroll
                for (int j = 0; j < 2; j++) {
                    short8 v;
                    #pragma unroll
                    for (int e = 0; e < 8; e++) v[e] = (short)xk[j * 8 + e];
                    *(short8*)(Xs + sx * 72 + kg * 16 + j * 8) = v;
                }
                __syncthreads();

                #pragma unroll
                for (int ks = 0; ks < 2; ks++) {
                    short8 Af[2], Bf[2];
                    #pragma unroll
                    for (int mf = 0; mf < 2; mf++)
                        Af[mf] = *(const short8*)(Wb + (wm + mf * 16 + l15) * 136 + chunk * 64 + ks * 32 + g4 * 8);
                    #pragma unroll
                    for (int nf = 0; nf < 2; nf++)
                        Bf[nf] = *(const short8*)(Xs + (wn + nf * 16 + l15) * 72 + ks * 32 + g4 * 8);
                    #pragma unroll
                    for (int mf = 0; mf < 2; mf++)
                        #pragma unroll
                        for (int nf = 0; nf < 2; nf++)
                            acc[mf][nf] = __builtin_amdgcn_mfma_f32_16x16x32_bf16(Af[mf], Bf[nf], acc[mf][nf], 0, 0, 0);
                }
            }

            __syncthreads();
            #pragma unroll
            for (int mf = 0; mf < 2; mf++)
                #pragma unroll
                for (int nf = 0; nf < 2; nf++) {
                    int s  = wn + nf * 16 + l15;
                    int mb = wm + mf * 16 + g4 * 4;
                    *(f32x4*)(T + s * 68 + mb) = acc[mf][nf];
                }
            __syncthreads();
            #pragma unroll
            for (int i = 0; i < 4; i++) {
                int f = t + i * 256;
                int og = f & 15, sl = f >> 4;
                float4 v = *(float4*)(T + sl * 68 + og * 4);
                int o_g = o0 + og * 4;
                v.x += bqkv[o_g]; v.y += bqkv[o_g + 1]; v.z += bqkv[o_g + 2]; v.w += bqkv[o_g + 3];
                int part = o_g >> 7, pc = o_g & 127;
                int head = pc >> 5, ic = pc & 31;
                size_t base = (((size_t)b * NHEAD + head) * SVOX + s0 + sl) * HDIM + ic;
                ushort4 u;
                u.x = f2h(v.x); u.y = f2h(v.y); u.z = f2h(v.z); u.w = f2h(v.w);
                ushort* dst = (part == 0) ? q_out : (part == 1) ? k_out : v_out;
                *(ushort4*)(dst + base) = u;
            }
        }
    }

    grid.sync();

    // ================= Phase 2: attention (1728 brick-heads) =================
    {
        ushort* Kl = (ushort*)smem;                  // [240][32] f16
        ushort* Vl = (ushort*)(smem + 15360);        // [240][32] f16

        for (int idx = blockIdx.x; idx < 1728; idx += gridDim.x) {
            const int b  = idx / 864;
            const int r  = idx - b * 864;
            const int n  = r / 216;
            const int br = r % 216;
            const int bw_ = br % 3, bh_ = (br / 3) % 6, bd_ = br / 18;
            const int d0 = bd_ * BD, h0 = bh_ * BH, w0 = bw_ * BW;
            __syncthreads();   // prev-iter Vl reads vs new staging writes

            const ushort* kb = k_out + ((size_t)b * NHEAD + n) * (size_t)SVOX * HDIM;
            const ushort* vb = v_out + ((size_t)b * NHEAD + n) * (size_t)SVOX * HDIM;

            #pragma unroll
            for (int i = 0; i < 4; i++) {
                int f = t + i * 256;
                if (f < NWIN * 4) {
                    int u = f >> 2, ch = f & 3;
                    int ud = u / (WH * WW);
                    int rr = u - ud * (WH * WW);
                    int uh = rr / WW;
                    int uw = rr - uh * WW;
                    int gd = d0 + ud - 1, gh = h0 + uh - 1, gw = w0 + uw - 1;
                    bool valid = ((unsigned)gd < 24u) & ((unsigned)gh < 24u) & ((unsigned)gw < 24u);
                    size_t gsv = valid ? (size_t)(gd * 576 + gh * 24 + gw) : 0;
                    uint4 kv = *(const uint4*)(kb + gsv * HDIM + ch * 8);
                    uint4 vv = *(const uint4*)(vb + gsv * HDIM + ch * 8);
                    if (!valid) { kv = make_uint4(0,0,0,0); vv = make_uint4(0,0,0,0); }
                    *(uint4*)(Kl + u * 32 + ch * 8) = kv;
                    *(uint4*)(Vl + u * 32 + ch * 8) = vv;
                }
            }

            const int p   = t >> 2;
            const int sub = t & 3;
            const int pw = p & 7, ph = (p >> 3) & 3, pd = p >> 5;
            const int sv = (d0 + pd) * 576 + (h0 + ph) * 24 + w0 + pw;
            uint4 qpk = *(const uint4*)(q_out + (((size_t)b * NHEAD + n) * SVOX + sv) * HDIM + sub * 8);

            float sc[27];
            #pragma unroll
            for (int s = 0; s < 27; s++) {
                uint4 pp = *(const uint4*)(pe + s * 16 + sub * 4);
                sc[s] = dot8h(qpk, pp, 0.f);
            }

            __syncthreads();

            const int wc = (pd + 1) * (WH * WW) + (ph + 1) * WW + (pw + 1);
            const ushort* Kbase = Kl + wc * 32 + sub * 8;

            #pragma unroll
            for (int s = 0; s < 27; s++) {
                const int di = s / 9 - 1, dj = (s / 3) % 3 - 1, dl = s % 3 - 1;
                const int off = (di * (WH * WW) + dj * WW + dl) * 32;
                uint4 kk = *(const uint4*)(Kbase + off);
                sc[s] = dot8h(qpk, kk, sc[s]);
            }

            #pragma unroll
            for (int s = 0; s < 27; s++) {
                sc[s] += quad_dpp<0xB1>(sc[s]);
                sc[s] += quad_dpp<0x4E>(sc[s]);
            }

            float m3[9];
            #pragma unroll
            for (int j = 0; j < 9; j++)
                m3[j] = fmaxf(fmaxf(sc[3*j], sc[3*j+1]), sc[3*j+2]);
            float m9a = fmaxf(fmaxf(m3[0], m3[1]), m3[2]);
            float m9b = fmaxf(fmaxf(m3[3], m3[4]), m3[5]);
            float m9c = fmaxf(fmaxf(m3[6], m3[7]), m3[8]);
            float mx  = fmaxf(fmaxf(m9a, m9b), m9c);

            const float KS = 0.17677669529663687f * 1.4426950408889634f;
            float sum = 0.f;
            #pragma unroll
            for (int s = 0; s < 27; s++) {
                float e = exp2f((sc[s] - mx) * KS);
                sc[s] = e;
                sum += e;
            }
            float inv = 1.f / sum;

            const ushort* Vbase = Vl + wc * 32 + sub * 8;
            __half2 o2[4];
            __half2 hz = __float2half2_rn(0.f);
            o2[0] = hz; o2[1] = hz; o2[2] = hz; o2[3] = hz;
            #pragma unroll
            for (int s = 0; s < 27; s++) {
                const int di = s / 9 - 1, dj = (s / 3) % 3 - 1, dl = s % 3 - 1;
                const int off = (di * (WH * WW) + dj * WW + dl) * 32;
                uint4 vv = *(const uint4*)(Vbase + off);
                __half2 p2 = splat_h2(sc[s] * inv);
                o2[0] = __hfma2(p2, u2h2(vv.x), o2[0]);
                o2[1] = __hfma2(p2, u2h2(vv.y), o2[1]);
                o2[2] = __hfma2(p2, u2h2(vv.z), o2[2]);
                o2[3] = __hfma2(p2, u2h2(vv.w), o2[3]);
            }

            union { __half2 h[4]; uint4 u; } ou;
            ou.h[0] = o2[0]; ou.h[1] = o2[1]; ou.h[2] = o2[2]; ou.h[3] = o2[3];
            *(uint4*)(attn_o + ((size_t)b * SVOX + sv) * CIN + n * HDIM + sub * 8) = ou.u;
        }
    }

    grid.sync();

    // ================= Phase 3: proj GEMM (864 tiles, f16 MFMA) =================
    {
        ushort* Wb = (ushort*)smem;                 // [64][136] f16
        ushort* Xs = (ushort*)(smem + 17408);       // [64 s][136 k] f16
        float*  T  = (float*)smem;

        const int lane = t & 63, wid = t >> 6, l15 = lane & 15, g4 = lane >> 4;
        const int wm = (wid >> 1) * 32, wn = (wid & 1) * 32;

        for (int idx = blockIdx.x; idx < 864; idx += gridDim.x) {
            const int b  = idx / 432;
            const int r  = idx - b * 432;
            const int o0 = (r / 216) * 64;
            const int s0 = (r % 216) * 64;
            __syncthreads();

            #pragma unroll
            for (int i = 0; i < 8; i++) {
                int f = t + i * 256;
                int row = f >> 5, c4 = f & 31;
                float4 w = *(const float4*)(Wp + (size_t)(o0 + row) * CIN + c4 * 4);
                ushort4 u;
                u.x = f2h(w.x); u.y = f2h(w.y); u.z = f2h(w.z); u.w = f2h(w.w);
                *(ushort4*)(Wb + row * 136 + c4 * 4) = u;
            }
            #pragma unroll
            for (int i = 0; i < 4; i++) {
                int f = t + i * 256;
                int row = f >> 4, c8 = f & 15;
                *(uint4*)(Xs + row * 136 + c8 * 8) =
                    *(const uint4*)(attn_o + ((size_t)b * SVOX + s0 + row) * CIN + c8 * 8);
            }
            __syncthreads();

            f32x4 acc[2][2];
            #pragma unroll
            for (int mf = 0; mf < 2; mf++)
                #pragma unroll
                for (int nf = 0; nf < 2; nf++)
                    acc[mf][nf] = (f32x4){0.f, 0.f, 0.f, 0.f};

            #pragma unroll
            for (int ks = 0; ks < 4; ks++) {
                half8 Af[2], Bf[2];
                #pragma unroll
                for (int mf = 0; mf < 2; mf++)
                    Af[mf] = __builtin_bit_cast(half8, *(const short8*)(Wb + (wm + mf * 16 + l15) * 136 + ks * 32 + g4 * 8));
                #pragma unroll
                for (int nf = 0; nf < 2; nf++)
                    Bf[nf] = __builtin_bit_cast(half8, *(const short8*)(Xs + (wn + nf * 16 + l15) * 136 + ks * 32 + g4 * 8));
                #pragma unroll
                for (int mf = 0; mf < 2; mf++)
                    #pragma unroll
                    for (int nf = 0; nf < 2; nf++)
                        acc[mf][nf] = __builtin_amdgcn_mfma_f32_16x16x32_f16(Af[mf], Bf[nf], acc[mf][nf], 0, 0, 0);
            }

            __syncthreads();
            #pragma unroll
            for (int mf = 0; mf < 2; mf++)
                #pragma unroll
                for (int nf = 0; nf < 2; nf++) {
                    int s  = wn + nf * 16 + l15;
                    int mb = wm + mf * 16 + g4 * 4;
                    #pragma unroll
                    for (int rr = 0; rr < 4; rr++)
                        T[(mb + rr) * 72 + s] = acc[mf][nf][rr];
                }
            __syncthreads();
            #pragma unroll
            for (int i = 0; i < 4; i++) {
                int f = t + i * 256;
                int s4 = f & 15, m = f >> 4;
                float4 v = *(float4*)(T + m * 72 + s4 * 4);
                float bi = bp[o0 + m];
                v.x += bi; v.y += bi; v.z += bi; v.w += bi;
                *(float4*)(out + ((size_t)b * CIN + o0 + m) * SVOX + s0 + s4 * 4) = v;
            }
        }
    }
}

extern "C" void kernel_launch(void* const* d_in, const int* in_sizes, int n_in,
                              void* d_out, int out_size, void* d_ws, size_t ws_size,
                              hipStream_t stream) {
    const float* x      = (const float*)d_in[0];
    const float* qkv_w  = (const float*)d_in[1];
    const float* qkv_b  = (const float*)d_in[2];
    const float* proj_w = (const float*)d_in[3];
    const float* proj_b = (const float*)d_in[4];
    const float* pos    = (const float*)d_in[5];
    float* out = (float*)d_out;

    const size_t HSZ = (size_t)2 * NHEAD * SVOX * HDIM;   // elems per q/k/v tensor
    ushort* qb  = (ushort*)d_ws;                          // f16 [2][4][S][32]
    ushort* kbp = qb + HSZ;                               // f16
    ushort* vbp = kbp + HSZ;                              // f16
    ushort* attn_o = vbp + HSZ;                           // f16 [2][S][128]
    unsigned* pe_p = (unsigned*)(attn_o + HSZ);           // [27][16] packed f16 pairs

    int nb = 0;
    if (hipOccupancyMaxActiveBlocksPerMultiprocessor(&nb, fused_kernel, 256, 0) != hipSuccess || nb < 1)
        nb = 1;
    if (nb > 4) nb = 4;
    dim3 grid(nb * 256), block(256);

    void* args[] = { (void*)&x, (void*)&qkv_w, (void*)&qkv_b, (void*)&proj_w, (void*)&proj_b,
                     (void*)&pos, (void*)&out, (void*)&qb, (void*)&kbp, (void*)&vbp,
                     (void*)&attn_o, (void*)&pe_p };
    hipLaunchCooperativeKernel(fused_kernel, grid, block, args, 0, stream);
}

// Round 19
// 200.751 us; speedup vs baseline: 1.0116x; 1.0116x over previous
//
#include <hip/hip_runtime.h>
#include <hip/hip_cooperative_groups.h>
#include <hip/hip_bf16.h>
#include <hip/hip_fp16.h>

namespace cg = cooperative_groups;

#define SVOX 13824   // 24*24*24
#define CIN 128
#define NHEAD 4
#define HDIM 32

// attention brick geometry: 2x4x8 voxels, 256 threads (4 lanes/voxel)
#define BD 2
#define BH 4
#define BW 8
#define WD (BD+2)
#define WH (BH+2)
#define WW (BW+2)
#define NWIN (WD*WH*WW)   // 240

typedef __attribute__((ext_vector_type(8))) short short8;
typedef __attribute__((ext_vector_type(8))) _Float16 half8;
typedef __attribute__((ext_vector_type(4))) float f32x4;
typedef __attribute__((ext_vector_type(2))) _Float16 h2v;
#if defined(__has_builtin)
#if __has_builtin(__builtin_amdgcn_fdot2)
#define HAVE_FDOT2 1
#endif
#if __has_builtin(__builtin_amdgcn_mov_dpp)
#define HAVE_DPP 1
#endif
#if __has_builtin(__builtin_amdgcn_cvt_pkrtz)
#define HAVE_PKRTZ 1
#endif
#endif

__device__ __forceinline__ unsigned short f2bf(float x) {
    unsigned u = __float_as_uint(x);
    u += 0x7FFFu + ((u >> 16) & 1u);
    return (unsigned short)(u >> 16);
}
__device__ __forceinline__ unsigned short f2h(float x) {
    return __builtin_bit_cast(unsigned short, (_Float16)x);
}
__device__ __forceinline__ __half2 u2h2(unsigned u) {
    union { unsigned u; __half2 h; } c; c.u = u; return c.h;
}
__device__ __forceinline__ float dot2h(unsigned a, unsigned b, float c) {
#ifdef HAVE_FDOT2
    return __builtin_amdgcn_fdot2(__builtin_bit_cast(h2v, a),
                                  __builtin_bit_cast(h2v, b), c, false);
#else
    __half2 p = __hmul2(u2h2(a), u2h2(b));
    return c + __low2float(p) + __high2float(p);
#endif
}
__device__ __forceinline__ float dot8h(uint4 a, uint4 b, float c) {
    c = dot2h(a.x, b.x, c); c = dot2h(a.y, b.y, c);
    c = dot2h(a.z, b.z, c); c = dot2h(a.w, b.w, c);
    return c;
}
template<int CTRL>
__device__ __forceinline__ float quad_dpp(float x) {
#ifdef HAVE_DPP
    return __int_as_float(__builtin_amdgcn_mov_dpp(__float_as_int(x), CTRL, 0xf, 0xf, true));
#else
    return __shfl_xor(x, (CTRL == 0xB1) ? 1 : 2);
#endif
}
__device__ __forceinline__ __half2 splat_h2(float x) {
#ifdef HAVE_PKRTZ
    auto v = __builtin_amdgcn_cvt_pkrtz(x, x);
    union { decltype(v) a; __half2 h; } c; c.a = v; return c.h;
#else
    return __float2half2_rn(x);
#endif
}

// ---------------------------------------------------------------------------
// Fused pipeline: phase1 qkv GEMM -> grid.sync -> phase2 attn -> grid.sync
// -> phase3 proj GEMM. launch_bounds(256,2): VGPR cap 256 so attn's sc[27]
// stays in registers (R18's (256,4) cap=128->compiler chose 60 and SPILLED).
// ---------------------------------------------------------------------------
__global__ __launch_bounds__(256, 2) void fused_kernel(
    const float* __restrict__ X,
    const float* __restrict__ Wqkv,
    const float* __restrict__ bqkv,
    const float* __restrict__ Wp,
    const float* __restrict__ bp,
    const float* __restrict__ pos,
    float* __restrict__ out,
    ushort* __restrict__ q_out,
    ushort* __restrict__ k_out,
    ushort* __restrict__ v_out,
    ushort* __restrict__ attn_o,
    unsigned* __restrict__ pe)
{
    __shared__ __align__(16) unsigned char smem[34816];
    const int t = threadIdx.x;
    cg::grid_group grid = cg::this_grid();

    // ================= Phase 1: QKV GEMM (2592 tiles) =================
    {
        ushort* Wb = (ushort*)smem;                 // [64][136] bf16
        ushort* Xs = (ushort*)(smem + 17408);       // [64 s][72 k] bf16
        float*  T  = (float*)smem;                  // epilogue alias

        const int lane = t & 63, wid = t >> 6, l15 = lane & 15, g4 = lane >> 4;
        const int wm = (wid >> 1) * 32, wn = (wid & 1) * 32;
        const int sx = t & 63, kg = t >> 6;

        if (blockIdx.x == 0)
            for (int i = t; i < 27 * 16; i += 256) {
                int w = i >> 4, cp = i & 15;
                pe[i] = (unsigned)f2h(pos[(2 * cp) * 27 + w])
                      | ((unsigned)f2h(pos[(2 * cp + 1) * 27 + w]) << 16);
            }

        for (int idx = blockIdx.x; idx < 2592; idx += gridDim.x) {
            const int b  = idx / 1296;
            const int r  = idx - b * 1296;
            const int o0 = (r / 216) * 64;
            const int s0 = (r % 216) * 64;
            __syncthreads();   // prev-iter T reads vs new Wb writes

            #pragma unroll
            for (int i = 0; i < 8; i++) {
                int f = t + i * 256;
                int row = f >> 5, c4 = f & 31;
                float4 w = *(const float4*)(Wqkv + (size_t)(o0 + row) * CIN + c4 * 4);
                ushort4 u;
                u.x = f2bf(w.x); u.y = f2bf(w.y); u.z = f2bf(w.z); u.w = f2bf(w.w);
                *(ushort4*)(Wb + row * 136 + c4 * 4) = u;
            }

            f32x4 acc[2][2];
            #pragma unroll
            for (int mf = 0; mf < 2; mf++)
                #pragma unroll
                for (int nf = 0; nf < 2; nf++)
                    acc[mf][nf] = (f32x4){0.f, 0.f, 0.f, 0.f};

            for (int chunk = 0; chunk < 2; chunk++) {
                __syncthreads();
                ushort xk[16];
                #pragma unroll
                for (int i = 0; i < 16; i++) {
                    int k = kg * 16 + i;
                    xk[i] = f2bf(X[((size_t)b * CIN + chunk * 64 + k) * SVOX + s0 + sx]);
                }
                #pragma unroll
                for (int j = 0; j < 2; j++) {
                    short8 v;
                    #pragma unroll
                    for (int e = 0; e < 8; e++) v[e] = (short)xk[j * 8 + e];
                    *(short8*)(Xs + sx * 72 + kg * 16 + j * 8) = v;
                }
                __syncthreads();

                #pragma unroll
                for (int ks = 0; ks < 2; ks++) {
                    short8 Af[2], Bf[2];
                    #pragma unroll
                    for (int mf = 0; mf < 2; mf++)
                        Af[mf] = *(const short8*)(Wb + (wm + mf * 16 + l15) * 136 + chunk * 64 + ks * 32 + g4 * 8);
                    #pragma unroll
                    for (int nf = 0; nf < 2; nf++)
                        Bf[nf] = *(const short8*)(Xs + (wn + nf * 16 + l15) * 72 + ks * 32 + g4 * 8);
                    #pragma unroll
                    for (int mf = 0; mf < 2; mf++)
                        #pragma unroll
                        for (int nf = 0; nf < 2; nf++)
                            acc[mf][nf] = __builtin_amdgcn_mfma_f32_16x16x32_bf16(Af[mf], Bf[nf], acc[mf][nf], 0, 0, 0);
                }
            }

            __syncthreads();
            #pragma unroll
            for (int mf = 0; mf < 2; mf++)
                #pragma unroll
                for (int nf = 0; nf < 2; nf++) {
                    int s  = wn + nf * 16 + l15;
                    int mb = wm + mf * 16 + g4 * 4;
                    *(f32x4*)(T + s * 68 + mb) = acc[mf][nf];
                }
            __syncthreads();
            #pragma unroll
            for (int i = 0; i < 4; i++) {
                int f = t + i * 256;
                int og = f & 15, sl = f >> 4;
                float4 v = *(float4*)(T + sl * 68 + og * 4);
                int o_g = o0 + og * 4;
                v.x += bqkv[o_g]; v.y += bqkv[o_g + 1]; v.z += bqkv[o_g + 2]; v.w += bqkv[o_g + 3];
                int part = o_g >> 7, pc = o_g & 127;
                int head = pc >> 5, ic = pc & 31;
                size_t base = (((size_t)b * NHEAD + head) * SVOX + s0 + sl) * HDIM + ic;
                ushort4 u;
                u.x = f2h(v.x); u.y = f2h(v.y); u.z = f2h(v.z); u.w = f2h(v.w);
                ushort* dst = (part == 0) ? q_out : (part == 1) ? k_out : v_out;
                *(ushort4*)(dst + base) = u;
            }
        }
    }

    grid.sync();

    // ================= Phase 2: attention (1728 brick-heads) =================
    {
        ushort* Kl = (ushort*)smem;                  // [240][32] f16
        ushort* Vl = (ushort*)(smem + 15360);        // [240][32] f16

        for (int idx = blockIdx.x; idx < 1728; idx += gridDim.x) {
            const int b  = idx / 864;
            const int r  = idx - b * 864;
            const int n  = r / 216;
            const int br = r % 216;
            const int bw_ = br % 3, bh_ = (br / 3) % 6, bd_ = br / 18;
            const int d0 = bd_ * BD, h0 = bh_ * BH, w0 = bw_ * BW;
            __syncthreads();   // prev-iter Vl reads vs new staging writes

            const ushort* kb = k_out + ((size_t)b * NHEAD + n) * (size_t)SVOX * HDIM;
            const ushort* vb = v_out + ((size_t)b * NHEAD + n) * (size_t)SVOX * HDIM;

            #pragma unroll
            for (int i = 0; i < 4; i++) {
                int f = t + i * 256;
                if (f < NWIN * 4) {
                    int u = f >> 2, ch = f & 3;
                    int ud = u / (WH * WW);
                    int rr = u - ud * (WH * WW);
                    int uh = rr / WW;
                    int uw = rr - uh * WW;
                    int gd = d0 + ud - 1, gh = h0 + uh - 1, gw = w0 + uw - 1;
                    bool valid = ((unsigned)gd < 24u) & ((unsigned)gh < 24u) & ((unsigned)gw < 24u);
                    size_t gsv = valid ? (size_t)(gd * 576 + gh * 24 + gw) : 0;
                    uint4 kv = *(const uint4*)(kb + gsv * HDIM + ch * 8);
                    uint4 vv = *(const uint4*)(vb + gsv * HDIM + ch * 8);
                    if (!valid) { kv = make_uint4(0,0,0,0); vv = make_uint4(0,0,0,0); }
                    *(uint4*)(Kl + u * 32 + ch * 8) = kv;
                    *(uint4*)(Vl + u * 32 + ch * 8) = vv;
                }
            }

            const int p   = t >> 2;
            const int sub = t & 3;
            const int pw = p & 7, ph = (p >> 3) & 3, pd = p >> 5;
            const int sv = (d0 + pd) * 576 + (h0 + ph) * 24 + w0 + pw;
            uint4 qpk = *(const uint4*)(q_out + (((size_t)b * NHEAD + n) * SVOX + sv) * HDIM + sub * 8);

            float sc[27];
            #pragma unroll
            for (int s = 0; s < 27; s++) {
                uint4 pp = *(const uint4*)(pe + s * 16 + sub * 4);
                sc[s] = dot8h(qpk, pp, 0.f);
            }

            __syncthreads();

            const int wc = (pd + 1) * (WH * WW) + (ph + 1) * WW + (pw + 1);
            const ushort* Kbase = Kl + wc * 32 + sub * 8;

            #pragma unroll
            for (int s = 0; s < 27; s++) {
                const int di = s / 9 - 1, dj = (s / 3) % 3 - 1, dl = s % 3 - 1;
                const int off = (di * (WH * WW) + dj * WW + dl) * 32;
                uint4 kk = *(const uint4*)(Kbase + off);
                sc[s] = dot8h(qpk, kk, sc[s]);
            }

            #pragma unroll
            for (int s = 0; s < 27; s++) {
                sc[s] += quad_dpp<0xB1>(sc[s]);
                sc[s] += quad_dpp<0x4E>(sc[s]);
            }

            float m3[9];
            #pragma unroll
            for (int j = 0; j < 9; j++)
                m3[j] = fmaxf(fmaxf(sc[3*j], sc[3*j+1]), sc[3*j+2]);
            float m9a = fmaxf(fmaxf(m3[0], m3[1]), m3[2]);
            float m9b = fmaxf(fmaxf(m3[3], m3[4]), m3[5]);
            float m9c = fmaxf(fmaxf(m3[6], m3[7]), m3[8]);
            float mx  = fmaxf(fmaxf(m9a, m9b), m9c);

            const float KS = 0.17677669529663687f * 1.4426950408889634f;
            float sum = 0.f;
            #pragma unroll
            for (int s = 0; s < 27; s++) {
                float e = exp2f((sc[s] - mx) * KS);
                sc[s] = e;
                sum += e;
            }
            float inv = 1.f / sum;

            const ushort* Vbase = Vl + wc * 32 + sub * 8;
            __half2 o2[4];
            __half2 hz = __float2half2_rn(0.f);
            o2[0] = hz; o2[1] = hz; o2[2] = hz; o2[3] = hz;
            #pragma unroll
            for (int s = 0; s < 27; s++) {
                const int di = s / 9 - 1, dj = (s / 3) % 3 - 1, dl = s % 3 - 1;
                const int off = (di * (WH * WW) + dj * WW + dl) * 32;
                uint4 vv = *(const uint4*)(Vbase + off);
                __half2 p2 = splat_h2(sc[s] * inv);
                o2[0] = __hfma2(p2, u2h2(vv.x), o2[0]);
                o2[1] = __hfma2(p2, u2h2(vv.y), o2[1]);
                o2[2] = __hfma2(p2, u2h2(vv.z), o2[2]);
                o2[3] = __hfma2(p2, u2h2(vv.w), o2[3]);
            }

            union { __half2 h[4]; uint4 u; } ou;
            ou.h[0] = o2[0]; ou.h[1] = o2[1]; ou.h[2] = o2[2]; ou.h[3] = o2[3];
            *(uint4*)(attn_o + ((size_t)b * SVOX + sv) * CIN + n * HDIM + sub * 8) = ou.u;
        }
    }

    grid.sync();

    // ================= Phase 3: proj GEMM (864 tiles, f16 MFMA) =================
    {
        ushort* Wb = (ushort*)smem;                 // [64][136] f16
        ushort* Xs = (ushort*)(smem + 17408);       // [64 s][136 k] f16
        float*  T  = (float*)smem;

        const int lane = t & 63, wid = t >> 6, l15 = lane & 15, g4 = lane >> 4;
        const int wm = (wid >> 1) * 32, wn = (wid & 1) * 32;

        for (int idx = blockIdx.x; idx < 864; idx += gridDim.x) {
            const int b  = idx / 432;
            const int r  = idx - b * 432;
            const int o0 = (r / 216) * 64;
            const int s0 = (r % 216) * 64;
            __syncthreads();

            #pragma unroll
            for (int i = 0; i < 8; i++) {
                int f = t + i * 256;
                int row = f >> 5, c4 = f & 31;
                float4 w = *(const float4*)(Wp + (size_t)(o0 + row) * CIN + c4 * 4);
                ushort4 u;
                u.x = f2h(w.x); u.y = f2h(w.y); u.z = f2h(w.z); u.w = f2h(w.w);
                *(ushort4*)(Wb + row * 136 + c4 * 4) = u;
            }
            #pragma unroll
            for (int i = 0; i < 4; i++) {
                int f = t + i * 256;
                int row = f >> 4, c8 = f & 15;
                *(uint4*)(Xs + row * 136 + c8 * 8) =
                    *(const uint4*)(attn_o + ((size_t)b * SVOX + s0 + row) * CIN + c8 * 8);
            }
            __syncthreads();

            f32x4 acc[2][2];
            #pragma unroll
            for (int mf = 0; mf < 2; mf++)
                #pragma unroll
                for (int nf = 0; nf < 2; nf++)
                    acc[mf][nf] = (f32x4){0.f, 0.f, 0.f, 0.f};

            #pragma unroll
            for (int ks = 0; ks < 4; ks++) {
                half8 Af[2], Bf[2];
                #pragma unroll
                for (int mf = 0; mf < 2; mf++)
                    Af[mf] = __builtin_bit_cast(half8, *(const short8*)(Wb + (wm + mf * 16 + l15) * 136 + ks * 32 + g4 * 8));
                #pragma unroll
                for (int nf = 0; nf < 2; nf++)
                    Bf[nf] = __builtin_bit_cast(half8, *(const short8*)(Xs + (wn + nf * 16 + l15) * 136 + ks * 32 + g4 * 8));
                #pragma unroll
                for (int mf = 0; mf < 2; mf++)
                    #pragma unroll
                    for (int nf = 0; nf < 2; nf++)
                        acc[mf][nf] = __builtin_amdgcn_mfma_f32_16x16x32_f16(Af[mf], Bf[nf], acc[mf][nf], 0, 0, 0);
            }

            __syncthreads();
            #pragma unroll
            for (int mf = 0; mf < 2; mf++)
                #pragma unroll
                for (int nf = 0; nf < 2; nf++) {
                    int s  = wn + nf * 16 + l15;
                    int mb = wm + mf * 16 + g4 * 4;
                    #pragma unroll
                    for (int rr = 0; rr < 4; rr++)
                        T[(mb + rr) * 72 + s] = acc[mf][nf][rr];
                }
            __syncthreads();
            #pragma unroll
            for (int i = 0; i < 4; i++) {
                int f = t + i * 256;
                int s4 = f & 15, m = f >> 4;
                float4 v = *(float4*)(T + m * 72 + s4 * 4);
                float bi = bp[o0 + m];
                v.x += bi; v.y += bi; v.z += bi; v.w += bi;
                *(float4*)(out + ((size_t)b * CIN + o0 + m) * SVOX + s0 + s4 * 4) = v;
            }
        }
    }
}

extern "C" void kernel_launch(void* const* d_in, const int* in_sizes, int n_in,
                              void* d_out, int out_size, void* d_ws, size_t ws_size,
                              hipStream_t stream) {
    const float* x      = (const float*)d_in[0];
    const float* qkv_w  = (const float*)d_in[1];
    const float* qkv_b  = (const float*)d_in[2];
    const float* proj_w = (const float*)d_in[3];
    const float* proj_b = (const float*)d_in[4];
    const float* pos    = (const float*)d_in[5];
    float* out = (float*)d_out;

    const size_t HSZ = (size_t)2 * NHEAD * SVOX * HDIM;   // elems per q/k/v tensor
    ushort* qb  = (ushort*)d_ws;                          // f16 [2][4][S][32]
    ushort* kbp = qb + HSZ;                               // f16
    ushort* vbp = kbp + HSZ;                              // f16
    ushort* attn_o = vbp + HSZ;                           // f16 [2][S][128]
    unsigned* pe_p = (unsigned*)(attn_o + HSZ);           // [27][16] packed f16 pairs

    int nb = 0;
    if (hipOccupancyMaxActiveBlocksPerMultiprocessor(&nb, fused_kernel, 256, 0) != hipSuccess || nb < 1)
        nb = 1;
    dim3 grid(nb * 256), block(256);

    void* args[] = { (void*)&x, (void*)&qkv_w, (void*)&qkv_b, (void*)&proj_w, (void*)&proj_b,
                     (void*)&pos, (void*)&out, (void*)&qb, (void*)&kbp, (void*)&vbp,
                     (void*)&attn_o, (void*)&pe_p };
    hipLaunchCooperativeKernel(fused_kernel, grid, block, args, 0, stream);
}

// Round 20
// 47.127 us; speedup vs baseline: 4.3091x; 4.2597x over previous
//
#include <hip/hip_runtime.h>
#include <hip/hip_bf16.h>
#include <hip/hip_fp16.h>

#define SVOX 13824   // 24*24*24
#define CIN 128
#define NHEAD 4
#define HDIM 32

// attention brick geometry: 2x4x8 voxels, 256 threads (4 lanes/voxel)
#define BD 2
#define BH 4
#define BW 8
#define WD (BD+2)
#define WH (BH+2)
#define WW (BW+2)
#define NWIN (WD*WH*WW)   // 240

typedef __attribute__((ext_vector_type(8))) short short8;
typedef __attribute__((ext_vector_type(4))) float f32x4;
#if defined(__has_builtin)
#if __has_builtin(__builtin_amdgcn_mov_dpp)
#define HAVE_DPP 1
#endif
#if __has_builtin(__builtin_amdgcn_cvt_pkrtz)
#define HAVE_PKRTZ 1
#endif
#endif

__device__ __forceinline__ unsigned short f2bf(float x) {
    unsigned u = __float_as_uint(x);
    u += 0x7FFFu + ((u >> 16) & 1u);
    return (unsigned short)(u >> 16);
}
__device__ __forceinline__ unsigned short f2h(float x) {
    return __builtin_bit_cast(unsigned short, (_Float16)x);
}
__device__ __forceinline__ __half2 u2h2(unsigned u) {
    union { unsigned u; __half2 h; } c; c.u = u; return c.h;
}
// 8-channel packed-half fma: 4x v_pk_fma_f16 (guaranteed single-instr each)
__device__ __forceinline__ __half2 fma8h(uint4 a, uint4 b, __half2 acc) {
    acc = __hfma2(u2h2(a.x), u2h2(b.x), acc);
    acc = __hfma2(u2h2(a.y), u2h2(b.y), acc);
    acc = __hfma2(u2h2(a.z), u2h2(b.z), acc);
    acc = __hfma2(u2h2(a.w), u2h2(b.w), acc);
    return acc;
}
template<int CTRL>
__device__ __forceinline__ float quad_dpp(float x) {
#ifdef HAVE_DPP
    return __int_as_float(__builtin_amdgcn_mov_dpp(__float_as_int(x), CTRL, 0xf, 0xf, true));
#else
    return __shfl_xor(x, (CTRL == 0xB1) ? 1 : 2);
#endif
}
__device__ __forceinline__ __half2 splat_h2(float x) {
#ifdef HAVE_PKRTZ
    auto v = __builtin_amdgcn_cvt_pkrtz(x, x);
    union { decltype(v) a; __half2 h; } c; c.a = v; return c.h;
#else
    return __float2half2_rn(x);
#endif
}

// ---------------------------------------------------------------------------
// Kernel 1: QKV GEMM, pure bf16 MFMA. Block(0,0,0) also packs the pos table
// (f16 pairs). q,k,v all stored f16. (unchanged from R17)
// ---------------------------------------------------------------------------
__global__ __launch_bounds__(256) void qkv_gemm(
    const float* __restrict__ X,
    const float* __restrict__ W,
    const float* __restrict__ bias,
    const float* __restrict__ pos,
    unsigned* __restrict__ pe_out,
    ushort* __restrict__ q_out,
    ushort* __restrict__ k_out,
    ushort* __restrict__ v_out)
{
    __shared__ __align__(16) unsigned char smem[26624];
    ushort* Wb = (ushort*)smem;                 // [64][136] bf16
    ushort* Xs = (ushort*)(smem + 17408);       // [64 s][72 k] bf16
    float*  T  = (float*)smem;                  // epilogue alias [64][68]

    const int t    = threadIdx.x;
    const int s0   = blockIdx.x * 64;
    const int o0   = blockIdx.y * 64;
    const int b    = blockIdx.z;
    const int lane = t & 63;
    const int wid  = t >> 6;
    const int l15  = lane & 15;
    const int g4   = lane >> 4;
    const int wm   = (wid >> 1) * 32;
    const int wn   = (wid & 1) * 32;

    if (blockIdx.x == 0 && blockIdx.y == 0 && blockIdx.z == 0 && t < 27 * 16) {
        int w = t >> 4, cp = t & 15;
        unsigned lo = f2h(pos[(2 * cp) * 27 + w]);
        unsigned hi = f2h(pos[(2 * cp + 1) * 27 + w]);
        pe_out[t] = lo | (hi << 16);
    }

    #pragma unroll
    for (int i = 0; i < 8; i++) {
        int f = t + i * 256;
        int row = f >> 5, c4 = f & 31;
        float4 w = *(const float4*)(W + (size_t)(o0 + row) * CIN + c4 * 4);
        ushort4 u;
        u.x = f2bf(w.x); u.y = f2bf(w.y); u.z = f2bf(w.z); u.w = f2bf(w.w);
        *(ushort4*)(Wb + row * 136 + c4 * 4) = u;
    }

    f32x4 acc[2][2];
    #pragma unroll
    for (int mf = 0; mf < 2; mf++)
        #pragma unroll
        for (int nf = 0; nf < 2; nf++)
            acc[mf][nf] = (f32x4){0.f, 0.f, 0.f, 0.f};

    const int sx = t & 63;
    const int kg = t >> 6;

    for (int chunk = 0; chunk < 2; chunk++) {
        __syncthreads();
        ushort xk[16];
        #pragma unroll
        for (int i = 0; i < 16; i++) {
            int k = kg * 16 + i;
            xk[i] = f2bf(X[((size_t)b * CIN + chunk * 64 + k) * SVOX + s0 + sx]);
        }
        #pragma unroll
        for (int j = 0; j < 2; j++) {
            short8 v;
            #pragma unroll
            for (int e = 0; e < 8; e++) v[e] = (short)xk[j * 8 + e];
            *(short8*)(Xs + sx * 72 + kg * 16 + j * 8) = v;
        }
        __syncthreads();

        #pragma unroll
        for (int ks = 0; ks < 2; ks++) {
            short8 Af[2], Bf[2];
            #pragma unroll
            for (int mf = 0; mf < 2; mf++)
                Af[mf] = *(const short8*)(Wb + (wm + mf * 16 + l15) * 136 + chunk * 64 + ks * 32 + g4 * 8);
            #pragma unroll
            for (int nf = 0; nf < 2; nf++)
                Bf[nf] = *(const short8*)(Xs + (wn + nf * 16 + l15) * 72 + ks * 32 + g4 * 8);
            #pragma unroll
            for (int mf = 0; mf < 2; mf++)
                #pragma unroll
                for (int nf = 0; nf < 2; nf++)
                    acc[mf][nf] = __builtin_amdgcn_mfma_f32_16x16x32_bf16(Af[mf], Bf[nf], acc[mf][nf], 0, 0, 0);
        }
    }

    __syncthreads();
    #pragma unroll
    for (int mf = 0; mf < 2; mf++)
        #pragma unroll
        for (int nf = 0; nf < 2; nf++) {
            int s  = wn + nf * 16 + l15;
            int mb = wm + mf * 16 + g4 * 4;
            *(f32x4*)(T + s * 68 + mb) = acc[mf][nf];
        }
    __syncthreads();
    #pragma unroll
    for (int i = 0; i < 4; i++) {
        int f = t + i * 256;
        int og = f & 15, sl = f >> 4;
        float4 v = *(float4*)(T + sl * 68 + og * 4);
        int o_g = o0 + og * 4;
        v.x += bias[o_g]; v.y += bias[o_g + 1]; v.z += bias[o_g + 2]; v.w += bias[o_g + 3];
        int part = o_g >> 7, pc = o_g & 127;
        int head = pc >> 5, ic = pc & 31;
        size_t base = (((size_t)b * NHEAD + head) * SVOX + s0 + sl) * HDIM + ic;
        ushort4 u;
        u.x = f2h(v.x); u.y = f2h(v.y); u.z = f2h(v.z); u.w = f2h(v.w);
        ushort* dst = (part == 0) ? q_out : (part == 1) ? k_out : v_out;
        *(ushort4*)(dst + base) = u;
    }
}

// ---------------------------------------------------------------------------
// Kernel 2: brick-LDS windowed attention. Q,K,V,pe f16. QK + q.pos via
// packed v_pk_fma_f16 into per-slot half2 accumulators (4 instr/slot),
// one horizontal f32 convert per slot; softmax/reduce in f32.
// ---------------------------------------------------------------------------
__global__ __launch_bounds__(256, 5) void attn_kernel(
    const ushort* __restrict__ qbf,
    const ushort* __restrict__ kbf,
    const ushort* __restrict__ vhf,
    const unsigned* __restrict__ pe_g,
    ushort* __restrict__ aout)
{
    __shared__ __align__(16) ushort Kl[NWIN * 32];       // 15360 B (f16)
    __shared__ __align__(16) ushort Vl[NWIN * 32];       // 15360 B (f16)

    const int t = threadIdx.x;
    const int br = blockIdx.x;           // 216 bricks: 12(d) x 6(h) x 3(w)
    const int n  = blockIdx.y;
    const int b  = blockIdx.z;
    const int bw_ = br % 3;
    const int bh_ = (br / 3) % 6;
    const int bd_ = br / 18;
    const int d0 = bd_ * BD, h0 = bh_ * BH, w0 = bw_ * BW;

    const ushort* kb = kbf + ((size_t)b * NHEAD + n) * (size_t)SVOX * HDIM;
    const ushort* vb = vhf + ((size_t)b * NHEAD + n) * (size_t)SVOX * HDIM;

    #pragma unroll
    for (int i = 0; i < 4; i++) {
        int f = t + i * 256;
        if (f < NWIN * 4) {
            int u = f >> 2, ch = f & 3;
            int ud = u / (WH * WW);
            int r  = u - ud * (WH * WW);
            int uh = r / WW;
            int uw = r - uh * WW;
            int gd = d0 + ud - 1, gh = h0 + uh - 1, gw = w0 + uw - 1;
            bool valid = ((unsigned)gd < 24u) & ((unsigned)gh < 24u) & ((unsigned)gw < 24u);
            size_t gsv = valid ? (size_t)(gd * 576 + gh * 24 + gw) : 0;
            uint4 kv = *(const uint4*)(kb + gsv * HDIM + ch * 8);
            uint4 vv = *(const uint4*)(vb + gsv * HDIM + ch * 8);
            if (!valid) { kv = make_uint4(0,0,0,0); vv = make_uint4(0,0,0,0); }
            *(uint4*)(Kl + u * 32 + ch * 8) = kv;
            *(uint4*)(Vl + u * 32 + ch * 8) = vv;
        }
    }

    const int p   = t >> 2;          // local voxel 0..63
    const int sub = t & 3;           // 8-channel group
    const int pw = p & 7, ph = (p >> 3) & 3, pd = p >> 5;
    const int sv = (d0 + pd) * 576 + (h0 + ph) * 24 + w0 + pw;
    uint4 qpk = *(const uint4*)(qbf + (((size_t)b * NHEAD + n) * SVOX + sv) * HDIM + sub * 8);

    // q . pos partials: packed-half fma accumulators (overlaps staging)
    __half2 pa[27];
    __half2 hz = __float2half2_rn(0.f);
    #pragma unroll
    for (int s = 0; s < 27; s++) {
        uint4 pp = *(const uint4*)(pe_g + s * 16 + sub * 4);
        pa[s] = fma8h(qpk, pp, hz);
    }

    __syncthreads();

    const int wc = (pd + 1) * (WH * WW) + (ph + 1) * WW + (pw + 1);
    const ushort* Kbase = Kl + wc * 32 + sub * 8;

    float sc[27];
    #pragma unroll
    for (int s = 0; s < 27; s++) {
        const int di = s / 9 - 1, dj = (s / 3) % 3 - 1, dl = s % 3 - 1;
        const int off = (di * (WH * WW) + dj * WW + dl) * 32;
        uint4 kk = *(const uint4*)(Kbase + off);
        __half2 a = fma8h(qpk, kk, pa[s]);
        sc[s] = __low2float(a) + __high2float(a);
    }

    #pragma unroll
    for (int s = 0; s < 27; s++) {
        sc[s] += quad_dpp<0xB1>(sc[s]);   // xor 1
        sc[s] += quad_dpp<0x4E>(sc[s]);   // xor 2
    }

    float m3[9];
    #pragma unroll
    for (int j = 0; j < 9; j++)
        m3[j] = fmaxf(fmaxf(sc[3*j], sc[3*j+1]), sc[3*j+2]);
    float m9a = fmaxf(fmaxf(m3[0], m3[1]), m3[2]);
    float m9b = fmaxf(fmaxf(m3[3], m3[4]), m3[5]);
    float m9c = fmaxf(fmaxf(m3[6], m3[7]), m3[8]);
    float mx  = fmaxf(fmaxf(m9a, m9b), m9c);

    const float KS = 0.17677669529663687f * 1.4426950408889634f;
    float sum = 0.f;
    #pragma unroll
    for (int s = 0; s < 27; s++) {
        float e = exp2f((sc[s] - mx) * KS);
        sc[s] = e;
        sum += e;
    }
    float inv = 1.f / sum;

    const ushort* Vbase = Vl + wc * 32 + sub * 8;
    __half2 o2[4];
    o2[0] = hz; o2[1] = hz; o2[2] = hz; o2[3] = hz;
    #pragma unroll
    for (int s = 0; s < 27; s++) {
        const int di = s / 9 - 1, dj = (s / 3) % 3 - 1, dl = s % 3 - 1;
        const int off = (di * (WH * WW) + dj * WW + dl) * 32;
        uint4 vv = *(const uint4*)(Vbase + off);
        __half2 p2 = splat_h2(sc[s] * inv);
        o2[0] = __hfma2(p2, u2h2(vv.x), o2[0]);
        o2[1] = __hfma2(p2, u2h2(vv.y), o2[1]);
        o2[2] = __hfma2(p2, u2h2(vv.z), o2[2]);
        o2[3] = __hfma2(p2, u2h2(vv.w), o2[3]);
    }

    float o[8];
    #pragma unroll
    for (int j = 0; j < 4; j++) {
        o[2*j]   = __low2float(o2[j]);
        o[2*j+1] = __high2float(o2[j]);
    }

    uint4 ou;
    ou.x = (unsigned)f2bf(o[0]) | ((unsigned)f2bf(o[1]) << 16);
    ou.y = (unsigned)f2bf(o[2]) | ((unsigned)f2bf(o[3]) << 16);
    ou.z = (unsigned)f2bf(o[4]) | ((unsigned)f2bf(o[5]) << 16);
    ou.w = (unsigned)f2bf(o[6]) | ((unsigned)f2bf(o[7]) << 16);
    *(uint4*)(aout + ((size_t)b * SVOX + sv) * CIN + n * HDIM + sub * 8) = ou;
}

// ---------------------------------------------------------------------------
// Kernel 3: proj GEMM, pure bf16 MFMA (R17 version; attn_o is bf16).
// ---------------------------------------------------------------------------
__global__ __launch_bounds__(256) void proj_gemm(
    const ushort* __restrict__ Xa,
    const float* __restrict__ W,
    const float* __restrict__ bias,
    float* __restrict__ out)
{
    __shared__ __align__(16) unsigned char smem[34816];
    ushort* Wb = (ushort*)smem;                 // [64][136] bf16
    ushort* Xs = (ushort*)(smem + 17408);       // [64 s][136 k] bf16
    float*  T  = (float*)smem;                  // epilogue alias [64][72]

    const int t    = threadIdx.x;
    const int s0   = blockIdx.x * 64;
    const int o0   = blockIdx.y * 64;
    const int b    = blockIdx.z;
    const int lane = t & 63;
    const int wid  = t >> 6;
    const int l15  = lane & 15;
    const int g4   = lane >> 4;
    const int wm   = (wid >> 1) * 32;
    const int wn   = (wid & 1) * 32;

    #pragma unroll
    for (int i = 0; i < 8; i++) {
        int f = t + i * 256;
        int row = f >> 5, c4 = f & 31;
        float4 w = *(const float4*)(W + (size_t)(o0 + row) * CIN + c4 * 4);
        ushort4 u;
        u.x = f2bf(w.x); u.y = f2bf(w.y); u.z = f2bf(w.z); u.w = f2bf(w.w);
        *(ushort4*)(Wb + row * 136 + c4 * 4) = u;
    }
    #pragma unroll
    for (int i = 0; i < 4; i++) {
        int f = t + i * 256;
        int row = f >> 4, c8 = f & 15;
        *(uint4*)(Xs + row * 136 + c8 * 8) =
            *(const uint4*)(Xa + ((size_t)b * SVOX + s0 + row) * CIN + c8 * 8);
    }
    __syncthreads();

    f32x4 acc[2][2];
    #pragma unroll
    for (int mf = 0; mf < 2; mf++)
        #pragma unroll
        for (int nf = 0; nf < 2; nf++)
            acc[mf][nf] = (f32x4){0.f, 0.f, 0.f, 0.f};

    #pragma unroll
    for (int ks = 0; ks < 4; ks++) {
        short8 Af[2], Bf[2];
        #pragma unroll
        for (int mf = 0; mf < 2; mf++)
            Af[mf] = *(const short8*)(Wb + (wm + mf * 16 + l15) * 136 + ks * 32 + g4 * 8);
        #pragma unroll
        for (int nf = 0; nf < 2; nf++)
            Bf[nf] = *(const short8*)(Xs + (wn + nf * 16 + l15) * 136 + ks * 32 + g4 * 8);
        #pragma unroll
        for (int mf = 0; mf < 2; mf++)
            #pragma unroll
            for (int nf = 0; nf < 2; nf++)
                acc[mf][nf] = __builtin_amdgcn_mfma_f32_16x16x32_bf16(Af[mf], Bf[nf], acc[mf][nf], 0, 0, 0);
    }

    __syncthreads();
    #pragma unroll
    for (int mf = 0; mf < 2; mf++)
        #pragma unroll
        for (int nf = 0; nf < 2; nf++) {
            int s  = wn + nf * 16 + l15;
            int mb = wm + mf * 16 + g4 * 4;
            #pragma unroll
            for (int r = 0; r < 4; r++)
                T[(mb + r) * 72 + s] = acc[mf][nf][r];
        }
    __syncthreads();
    #pragma unroll
    for (int i = 0; i < 4; i++) {
        int f = t + i * 256;
        int s4 = f & 15, m = f >> 4;
        float4 v = *(float4*)(T + m * 72 + s4 * 4);
        float bi = bias[o0 + m];
        v.x += bi; v.y += bi; v.z += bi; v.w += bi;
        *(float4*)(out + ((size_t)b * CIN + o0 + m) * SVOX + s0 + s4 * 4) = v;
    }
}

extern "C" void kernel_launch(void* const* d_in, const int* in_sizes, int n_in,
                              void* d_out, int out_size, void* d_ws, size_t ws_size,
                              hipStream_t stream) {
    const float* x      = (const float*)d_in[0];
    const float* qkv_w  = (const float*)d_in[1];
    const float* qkv_b  = (const float*)d_in[2];
    const float* proj_w = (const float*)d_in[3];
    const float* proj_b = (const float*)d_in[4];
    const float* pos    = (const float*)d_in[5];
    float* out = (float*)d_out;

    const size_t HSZ = (size_t)2 * NHEAD * SVOX * HDIM;   // elems per q/k/v tensor
    ushort* qb  = (ushort*)d_ws;                          // f16 [2][4][S][32]
    ushort* kbp = qb + HSZ;                               // f16
    ushort* vbp = kbp + HSZ;                              // f16
    ushort* attn_o = vbp + HSZ;                           // bf16 [2][S][128]
    unsigned* pe_p = (unsigned*)(attn_o + HSZ);           // [27][16] packed f16 pairs

    qkv_gemm<<<dim3(SVOX/64, 384/64, 2), 256, 0, stream>>>(x, qkv_w, qkv_b, pos, pe_p, qb, kbp, vbp);
    attn_kernel<<<dim3(216, NHEAD, 2), 256, 0, stream>>>(qb, kbp, vbp, pe_p, attn_o);
    proj_gemm<<<dim3(SVOX/64, CIN/64, 2), 256, 0, stream>>>(attn_o, proj_w, proj_b, out);
}

// Round 21
// 45.736 us; speedup vs baseline: 4.4402x; 1.0304x over previous
//
#include <hip/hip_runtime.h>
#include <hip/hip_bf16.h>
#include <hip/hip_fp16.h>

#define SVOX 13824   // 24*24*24
#define CIN 128
#define NHEAD 4
#define HDIM 32

// attention brick geometry: 2x4x8 voxels, 256 threads (4 lanes/voxel)
#define BD 2
#define BH 4
#define BW 8
#define WD (BD+2)
#define WH (BH+2)
#define WW (BW+2)
#define NWIN (WD*WH*WW)   // 240

typedef __attribute__((ext_vector_type(8))) short short8;
typedef __attribute__((ext_vector_type(4))) float f32x4;
typedef __attribute__((ext_vector_type(2))) _Float16 h2v;
#if defined(__has_builtin)
#if __has_builtin(__builtin_amdgcn_fdot2)
#define HAVE_FDOT2 1
#endif
#if __has_builtin(__builtin_amdgcn_mov_dpp)
#define HAVE_DPP 1
#endif
#if __has_builtin(__builtin_amdgcn_cvt_pkrtz)
#define HAVE_PKRTZ 1
#endif
#endif

__device__ __forceinline__ unsigned short f2bf(float x) {
    unsigned u = __float_as_uint(x);
    u += 0x7FFFu + ((u >> 16) & 1u);
    return (unsigned short)(u >> 16);
}
__device__ __forceinline__ unsigned short f2h(float x) {
    return __builtin_bit_cast(unsigned short, (_Float16)x);
}
__device__ __forceinline__ __half2 u2h2(unsigned u) {
    union { unsigned u; __half2 h; } c; c.u = u; return c.h;
}
// f16 dot2 with f32 accumulate: v_dot2_f32_f16 (single instr on gfx9+)
__device__ __forceinline__ float dot2h(unsigned a, unsigned b, float c) {
#ifdef HAVE_FDOT2
    return __builtin_amdgcn_fdot2(__builtin_bit_cast(h2v, a),
                                  __builtin_bit_cast(h2v, b), c, false);
#else
    __half2 p = __hmul2(u2h2(a), u2h2(b));
    return c + __low2float(p) + __high2float(p);
#endif
}
__device__ __forceinline__ float dot8h(uint4 a, uint4 b, float c) {
    c = dot2h(a.x, b.x, c); c = dot2h(a.y, b.y, c);
    c = dot2h(a.z, b.z, c); c = dot2h(a.w, b.w, c);
    return c;
}
template<int CTRL>
__device__ __forceinline__ float quad_dpp(float x) {
#ifdef HAVE_DPP
    return __int_as_float(__builtin_amdgcn_mov_dpp(__float_as_int(x), CTRL, 0xf, 0xf, true));
#else
    return __shfl_xor(x, (CTRL == 0xB1) ? 1 : 2);
#endif
}
__device__ __forceinline__ __half2 splat_h2(float x) {
#ifdef HAVE_PKRTZ
    auto v = __builtin_amdgcn_cvt_pkrtz(x, x);
    union { decltype(v) a; __half2 h; } c; c.a = v; return c.h;
#else
    return __float2half2_rn(x);
#endif
}

// ---------------------------------------------------------------------------
// Kernel 1: QKV GEMM, pure bf16 MFMA. Block(0,0,0) also packs the pos table
// (f16 pairs). q,k,v all stored f16 (feeds v_dot2_f32_f16 QK + hfma2 PV).
// ---------------------------------------------------------------------------
__global__ __launch_bounds__(256) void qkv_gemm(
    const float* __restrict__ X,
    const float* __restrict__ W,
    const float* __restrict__ bias,
    const float* __restrict__ pos,
    unsigned* __restrict__ pe_out,
    ushort* __restrict__ q_out,
    ushort* __restrict__ k_out,
    ushort* __restrict__ v_out)
{
    __shared__ __align__(16) unsigned char smem[26624];
    ushort* Wb = (ushort*)smem;                 // [64][136] bf16
    ushort* Xs = (ushort*)(smem + 17408);       // [64 s][72 k] bf16
    float*  T  = (float*)smem;                  // epilogue alias [64][68]

    const int t    = threadIdx.x;
    const int s0   = blockIdx.x * 64;
    const int o0   = blockIdx.y * 64;
    const int b    = blockIdx.z;
    const int lane = t & 63;
    const int wid  = t >> 6;
    const int l15  = lane & 15;
    const int g4   = lane >> 4;
    const int wm   = (wid >> 1) * 32;
    const int wn   = (wid & 1) * 32;

    if (blockIdx.x == 0 && blockIdx.y == 0 && blockIdx.z == 0 && t < 27 * 16) {
        int w = t >> 4, cp = t & 15;
        unsigned lo = f2h(pos[(2 * cp) * 27 + w]);
        unsigned hi = f2h(pos[(2 * cp + 1) * 27 + w]);
        pe_out[t] = lo | (hi << 16);
    }

    #pragma unroll
    for (int i = 0; i < 8; i++) {
        int f = t + i * 256;
        int row = f >> 5, c4 = f & 31;
        float4 w = *(const float4*)(W + (size_t)(o0 + row) * CIN + c4 * 4);
        ushort4 u;
        u.x = f2bf(w.x); u.y = f2bf(w.y); u.z = f2bf(w.z); u.w = f2bf(w.w);
        *(ushort4*)(Wb + row * 136 + c4 * 4) = u;
    }

    f32x4 acc[2][2];
    #pragma unroll
    for (int mf = 0; mf < 2; mf++)
        #pragma unroll
        for (int nf = 0; nf < 2; nf++)
            acc[mf][nf] = (f32x4){0.f, 0.f, 0.f, 0.f};

    const int sx = t & 63;
    const int kg = t >> 6;

    for (int chunk = 0; chunk < 2; chunk++) {
        __syncthreads();
        ushort xk[16];
        #pragma unroll
        for (int i = 0; i < 16; i++) {
            int k = kg * 16 + i;
            xk[i] = f2bf(X[((size_t)b * CIN + chunk * 64 + k) * SVOX + s0 + sx]);
        }
        #pragma unroll
        for (int j = 0; j < 2; j++) {
            short8 v;
            #pragma unroll
            for (int e = 0; e < 8; e++) v[e] = (short)xk[j * 8 + e];
            *(short8*)(Xs + sx * 72 + kg * 16 + j * 8) = v;
        }
        __syncthreads();

        #pragma unroll
        for (int ks = 0; ks < 2; ks++) {
            short8 Af[2], Bf[2];
            #pragma unroll
            for (int mf = 0; mf < 2; mf++)
                Af[mf] = *(const short8*)(Wb + (wm + mf * 16 + l15) * 136 + chunk * 64 + ks * 32 + g4 * 8);
            #pragma unroll
            for (int nf = 0; nf < 2; nf++)
                Bf[nf] = *(const short8*)(Xs + (wn + nf * 16 + l15) * 72 + ks * 32 + g4 * 8);
            #pragma unroll
            for (int mf = 0; mf < 2; mf++)
                #pragma unroll
                for (int nf = 0; nf < 2; nf++)
                    acc[mf][nf] = __builtin_amdgcn_mfma_f32_16x16x32_bf16(Af[mf], Bf[nf], acc[mf][nf], 0, 0, 0);
        }
    }

    __syncthreads();
    #pragma unroll
    for (int mf = 0; mf < 2; mf++)
        #pragma unroll
        for (int nf = 0; nf < 2; nf++) {
            int s  = wn + nf * 16 + l15;
            int mb = wm + mf * 16 + g4 * 4;
            *(f32x4*)(T + s * 68 + mb) = acc[mf][nf];
        }
    __syncthreads();
    #pragma unroll
    for (int i = 0; i < 4; i++) {
        int f = t + i * 256;
        int og = f & 15, sl = f >> 4;
        float4 v = *(float4*)(T + sl * 68 + og * 4);
        int o_g = o0 + og * 4;
        v.x += bias[o_g]; v.y += bias[o_g + 1]; v.z += bias[o_g + 2]; v.w += bias[o_g + 3];
        int part = o_g >> 7, pc = o_g & 127;
        int head = pc >> 5, ic = pc & 31;
        size_t base = (((size_t)b * NHEAD + head) * SVOX + s0 + sl) * HDIM + ic;
        ushort4 u;
        u.x = f2h(v.x); u.y = f2h(v.y); u.z = f2h(v.z); u.w = f2h(v.w);
        ushort* dst = (part == 0) ? q_out : (part == 1) ? k_out : v_out;
        *(ushort4*)(dst + base) = u;
    }
}

// ---------------------------------------------------------------------------
// Kernel 2: brick-LDS windowed attention (R11 structure). Q,K,V,pe all f16;
// QK + q.pos via v_dot2_f32_f16 (f32 accumulate); PV via v_pk_fma_f16.
// ---------------------------------------------------------------------------
__global__ __launch_bounds__(256, 5) void attn_kernel(
    const ushort* __restrict__ qbf,
    const ushort* __restrict__ kbf,
    const ushort* __restrict__ vhf,
    const unsigned* __restrict__ pe_g,
    ushort* __restrict__ aout)
{
    __shared__ __align__(16) ushort Kl[NWIN * 32];       // 15360 B (f16)
    __shared__ __align__(16) ushort Vl[NWIN * 32];       // 15360 B (f16)

    const int t = threadIdx.x;
    const int br = blockIdx.x;           // 216 bricks: 12(d) x 6(h) x 3(w)
    const int n  = blockIdx.y;
    const int b  = blockIdx.z;
    const int bw_ = br % 3;
    const int bh_ = (br / 3) % 6;
    const int bd_ = br / 18;
    const int d0 = bd_ * BD, h0 = bh_ * BH, w0 = bw_ * BW;

    const ushort* kb = kbf + ((size_t)b * NHEAD + n) * (size_t)SVOX * HDIM;
    const ushort* vb = vhf + ((size_t)b * NHEAD + n) * (size_t)SVOX * HDIM;

    #pragma unroll
    for (int i = 0; i < 4; i++) {
        int f = t + i * 256;
        if (f < NWIN * 4) {
            int u = f >> 2, ch = f & 3;
            int ud = u / (WH * WW);
            int r  = u - ud * (WH * WW);
            int uh = r / WW;
            int uw = r - uh * WW;
            int gd = d0 + ud - 1, gh = h0 + uh - 1, gw = w0 + uw - 1;
            bool valid = ((unsigned)gd < 24u) & ((unsigned)gh < 24u) & ((unsigned)gw < 24u);
            size_t gsv = valid ? (size_t)(gd * 576 + gh * 24 + gw) : 0;
            uint4 kv = *(const uint4*)(kb + gsv * HDIM + ch * 8);
            uint4 vv = *(const uint4*)(vb + gsv * HDIM + ch * 8);
            if (!valid) { kv = make_uint4(0,0,0,0); vv = make_uint4(0,0,0,0); }
            *(uint4*)(Kl + u * 32 + ch * 8) = kv;
            *(uint4*)(Vl + u * 32 + ch * 8) = vv;
        }
    }

    const int p   = t >> 2;          // local voxel 0..63
    const int sub = t & 3;           // 8-channel group
    const int pw = p & 7, ph = (p >> 3) & 3, pd = p >> 5;
    const int sv = (d0 + pd) * 576 + (h0 + ph) * 24 + w0 + pw;
    uint4 qpk = *(const uint4*)(qbf + (((size_t)b * NHEAD + n) * SVOX + sv) * HDIM + sub * 8);

    // q . pos partials from global pe table (L1 broadcast), overlaps staging
    float sc[27];
    #pragma unroll
    for (int s = 0; s < 27; s++) {
        uint4 pp = *(const uint4*)(pe_g + s * 16 + sub * 4);
        sc[s] = dot8h(qpk, pp, 0.f);
    }

    __syncthreads();

    const int wc = (pd + 1) * (WH * WW) + (ph + 1) * WW + (pw + 1);
    const ushort* Kbase = Kl + wc * 32 + sub * 8;

    #pragma unroll
    for (int s = 0; s < 27; s++) {
        const int di = s / 9 - 1, dj = (s / 3) % 3 - 1, dl = s % 3 - 1;
        const int off = (di * (WH * WW) + dj * WW + dl) * 32;
        uint4 kk = *(const uint4*)(Kbase + off);
        sc[s] = dot8h(qpk, kk, sc[s]);
    }

    #pragma unroll
    for (int s = 0; s < 27; s++) {
        sc[s] += quad_dpp<0xB1>(sc[s]);   // xor 1
        sc[s] += quad_dpp<0x4E>(sc[s]);   // xor 2
    }

    float m3[9];
    #pragma unroll
    for (int j = 0; j < 9; j++)
        m3[j] = fmaxf(fmaxf(sc[3*j], sc[3*j+1]), sc[3*j+2]);
    float m9a = fmaxf(fmaxf(m3[0], m3[1]), m3[2]);
    float m9b = fmaxf(fmaxf(m3[3], m3[4]), m3[5]);
    float m9c = fmaxf(fmaxf(m3[6], m3[7]), m3[8]);
    float mx  = fmaxf(fmaxf(m9a, m9b), m9c);

    const float KS = 0.17677669529663687f * 1.4426950408889634f;
    float sum = 0.f;
    #pragma unroll
    for (int s = 0; s < 27; s++) {
        float e = exp2f((sc[s] - mx) * KS);
        sc[s] = e;
        sum += e;
    }
    float inv = 1.f / sum;

    const ushort* Vbase = Vl + wc * 32 + sub * 8;
    __half2 o2[4];
    __half2 hz = __float2half2_rn(0.f);
    o2[0] = hz; o2[1] = hz; o2[2] = hz; o2[3] = hz;
    #pragma unroll
    for (int s = 0; s < 27; s++) {
        const int di = s / 9 - 1, dj = (s / 3) % 3 - 1, dl = s % 3 - 1;
        const int off = (di * (WH * WW) + dj * WW + dl) * 32;
        uint4 vv = *(const uint4*)(Vbase + off);
        __half2 p2 = splat_h2(sc[s]);
        o2[0] = __hfma2(p2, u2h2(vv.x), o2[0]);
        o2[1] = __hfma2(p2, u2h2(vv.y), o2[1]);
        o2[2] = __hfma2(p2, u2h2(vv.z), o2[2]);
        o2[3] = __hfma2(p2, u2h2(vv.w), o2[3]);
    }

    float o[8];
    #pragma unroll
    for (int j = 0; j < 4; j++) {
        o[2*j]   = __low2float(o2[j]);
        o[2*j+1] = __high2float(o2[j]);
    }

    uint4 ou;
    ou.x = (unsigned)f2bf(o[0] * inv) | ((unsigned)f2bf(o[1] * inv) << 16);
    ou.y = (unsigned)f2bf(o[2] * inv) | ((unsigned)f2bf(o[3] * inv) << 16);
    ou.z = (unsigned)f2bf(o[4] * inv) | ((unsigned)f2bf(o[5] * inv) << 16);
    ou.w = (unsigned)f2bf(o[6] * inv) | ((unsigned)f2bf(o[7] * inv) << 16);
    *(uint4*)(aout + ((size_t)b * SVOX + sv) * CIN + n * HDIM + sub * 8) = ou;
}

// ---------------------------------------------------------------------------
// Kernel 3: proj GEMM, pure bf16 MFMA (attn_o is bf16).
// ---------------------------------------------------------------------------
__global__ __launch_bounds__(256) void proj_gemm(
    const ushort* __restrict__ Xa,
    const float* __restrict__ W,
    const float* __restrict__ bias,
    float* __restrict__ out)
{
    __shared__ __align__(16) unsigned char smem[34816];
    ushort* Wb = (ushort*)smem;                 // [64][136] bf16
    ushort* Xs = (ushort*)(smem + 17408);       // [64 s][136 k] bf16
    float*  T  = (float*)smem;                  // epilogue alias [64][72]

    const int t    = threadIdx.x;
    const int s0   = blockIdx.x * 64;
    const int o0   = blockIdx.y * 64;
    const int b    = blockIdx.z;
    const int lane = t & 63;
    const int wid  = t >> 6;
    const int l15  = lane & 15;
    const int g4   = lane >> 4;
    const int wm   = (wid >> 1) * 32;
    const int wn   = (wid & 1) * 32;

    #pragma unroll
    for (int i = 0; i < 8; i++) {
        int f = t + i * 256;
        int row = f >> 5, c4 = f & 31;
        float4 w = *(const float4*)(W + (size_t)(o0 + row) * CIN + c4 * 4);
        ushort4 u;
        u.x = f2bf(w.x); u.y = f2bf(w.y); u.z = f2bf(w.z); u.w = f2bf(w.w);
        *(ushort4*)(Wb + row * 136 + c4 * 4) = u;
    }
    #pragma unroll
    for (int i = 0; i < 4; i++) {
        int f = t + i * 256;
        int row = f >> 4, c8 = f & 15;
        *(uint4*)(Xs + row * 136 + c8 * 8) =
            *(const uint4*)(Xa + ((size_t)b * SVOX + s0 + row) * CIN + c8 * 8);
    }
    __syncthreads();

    f32x4 acc[2][2];
    #pragma unroll
    for (int mf = 0; mf < 2; mf++)
        #pragma unroll
        for (int nf = 0; nf < 2; nf++)
            acc[mf][nf] = (f32x4){0.f, 0.f, 0.f, 0.f};

    #pragma unroll
    for (int ks = 0; ks < 4; ks++) {
        short8 Af[2], Bf[2];
        #pragma unroll
        for (int mf = 0; mf < 2; mf++)
            Af[mf] = *(const short8*)(Wb + (wm + mf * 16 + l15) * 136 + ks * 32 + g4 * 8);
        #pragma unroll
        for (int nf = 0; nf < 2; nf++)
            Bf[nf] = *(const short8*)(Xs + (wn + nf * 16 + l15) * 136 + ks * 32 + g4 * 8);
        #pragma unroll
        for (int mf = 0; mf < 2; mf++)
            #pragma unroll
            for (int nf = 0; nf < 2; nf++)
                acc[mf][nf] = __builtin_amdgcn_mfma_f32_16x16x32_bf16(Af[mf], Bf[nf], acc[mf][nf], 0, 0, 0);
    }

    __syncthreads();
    #pragma unroll
    for (int mf = 0; mf < 2; mf++)
        #pragma unroll
        for (int nf = 0; nf < 2; nf++) {
            int s  = wn + nf * 16 + l15;
            int mb = wm + mf * 16 + g4 * 4;
            #pragma unroll
            for (int r = 0; r < 4; r++)
                T[(mb + r) * 72 + s] = acc[mf][nf][r];
        }
    __syncthreads();
    #pragma unroll
    for (int i = 0; i < 4; i++) {
        int f = t + i * 256;
        int s4 = f & 15, m = f >> 4;
        float4 v = *(float4*)(T + m * 72 + s4 * 4);
        float bi = bias[o0 + m];
        v.x += bi; v.y += bi; v.z += bi; v.w += bi;
        *(float4*)(out + ((size_t)b * CIN + o0 + m) * SVOX + s0 + s4 * 4) = v;
    }
}

extern "C" void kernel_launch(void* const* d_in, const int* in_sizes, int n_in,
                              void* d_out, int out_size, void* d_ws, size_t ws_size,
                              hipStream_t stream) {
    const float* x      = (const float*)d_in[0];
    const float* qkv_w  = (const float*)d_in[1];
    const float* qkv_b  = (const float*)d_in[2];
    const float* proj_w = (const float*)d_in[3];
    const float* proj_b = (const float*)d_in[4];
    const float* pos    = (const float*)d_in[5];
    float* out = (float*)d_out;

    const size_t HSZ = (size_t)2 * NHEAD * SVOX * HDIM;   // elems per q/k/v tensor
    ushort* qb  = (ushort*)d_ws;                          // f16 [2][4][S][32]
    ushort* kbp = qb + HSZ;                               // f16
    ushort* vbp = kbp + HSZ;                              // f16
    ushort* attn_o = vbp + HSZ;                           // bf16 [2][S][128]
    unsigned* pe_p = (unsigned*)(attn_o + HSZ);           // [27][16] packed f16 pairs

    qkv_gemm<<<dim3(SVOX/64, 384/64, 2), 256, 0, stream>>>(x, qkv_w, qkv_b, pos, pe_p, qb, kbp, vbp);
    attn_kernel<<<dim3(216, NHEAD, 2), 256, 0, stream>>>(qb, kbp, vbp, pe_p, attn_o);
    proj_gemm<<<dim3(SVOX/64, CIN/64, 2), 256, 0, stream>>>(attn_o, proj_w, proj_b, out);
}